// Round 10
// baseline (1333.462 us; speedup 1.0000x reference)
//
#include <hip/hip_runtime.h>
#include <hip/hip_bf16.h>

typedef __bf16 bf16x8 __attribute__((ext_vector_type(8)));
typedef float f32x4 __attribute__((ext_vector_type(4)));
typedef unsigned long long ull;

// d_out layout (f32): hs[128][64][1024] | h_n[64][1024] | c_n[64][1024]
#define HN_OFF 8388608u
#define CN_OFF 8454144u

__device__ __forceinline__ float bf2f(ushort u) {
  union { unsigned int i; float f; } x; x.i = ((unsigned int)u) << 16; return x.f;
}
__device__ __forceinline__ ushort f2bf(float f) {
  union { float f; unsigned int i; } x; x.f = f;
  unsigned int r = x.i + 0x7FFFu + ((x.i >> 16) & 1u);
  return (ushort)(r >> 16);
}
__device__ __forceinline__ unsigned pack2(float a, float b) {
  return (unsigned)f2bf(a) | ((unsigned)f2bf(b) << 16);
}

// h0 (64x1024 f32) -> blocked bf16 layout [bq(4)][kk(32)][lane(64)][8] (parity 0)
__global__ __launch_bounds__(256) void conv_h0(const float* __restrict__ h0,
                                               ushort* __restrict__ hb) {
  int t = blockIdx.x * 256 + threadIdx.x;  // 8192 threads: b = t>>7, chunk c = t&127
  int b = t >> 7, c = t & 127;             // j = c*8
  float4 v0 = *reinterpret_cast<const float4*>(h0 + (size_t)b * 1024 + c * 8);
  float4 v1 = *reinterpret_cast<const float4*>(h0 + (size_t)b * 1024 + c * 8 + 4);
  size_t de = ((size_t)(b >> 4) * 32 + (c >> 2)) * 512 + (size_t)(c & 3) * 128 + (b & 15) * 8;
  ushort* d = hb + de;
  d[0] = f2bf(v0.x); d[1] = f2bf(v0.y); d[2] = f2bf(v0.z); d[3] = f2bf(v0.w);
  d[4] = f2bf(v1.x); d[5] = f2bf(v1.y); d[6] = f2bf(v1.z); d[7] = f2bf(v1.w);
}

// ---------------- base[g][b] = input[b]·W_x[g] + b_ih[g] + b_hh[g] ----------------
__global__ __launch_bounds__(256) void base_kernel(const float* __restrict__ x,
    const float* __restrict__ Wih, const float* __restrict__ bih,
    const float* __restrict__ bhh, float* __restrict__ baseT) {
  int t = blockIdx.x * 256 + threadIdx.x;  // 4096*64 threads
  int g = t >> 6, b = t & 63;
  const float4* xv = reinterpret_cast<const float4*>(x + (size_t)b * 512);
  const float4* wv = reinterpret_cast<const float4*>(Wih + (size_t)g * 1024);
  float s = 0.f;
  #pragma unroll 4
  for (int a = 0; a < 128; ++a) {
    float4 xa = xv[a], wa = wv[a];
    s += xa.x * wa.x + xa.y * wa.y + xa.z * wa.z + xa.w * wa.w;
  }
  baseT[t] = s + bih[g] + bhh[g];
}

// =============================================================================
// MEGA kernel: blocks 0..255 = persistent LSTM recurrence (4 planes x 64 unit-
// groups, W_hh in registers); blocks 256..2303 = pre-GEMM tiles producing
// pre[l][g][b] (bf16, sc0sc1 write-through to MALL) gated by pre_ready[ntile].
// LSTM h exchange: cellLanes store h via sc0sc1 short stores; per-wave vmcnt
// drain; last wave of block (LDS counter) publishes monotonic flag; consumers
// spin per-lane on the 64 packed flags of their plane. No block barriers in
// the step loop.
// =============================================================================
#define WAITG(n) asm volatile("s_waitcnt vmcnt(" #n ")" ::: "memory"); \
                 __builtin_amdgcn_sched_barrier(0);

__global__ __launch_bounds__(256, 2) void mega_kernel(
    const float* __restrict__ Whh,   // f32 [4096][1024]
    const float* __restrict__ Wih,   // f32 [4096][1024] (cols 512.. = W_a)
    const float* __restrict__ acts,  // f32 [128*64][512]
    const float* __restrict__ c0,    // f32 [64][1024]
    const float* __restrict__ baseT, // f32 [4096][64]
    ushort* hbuf,                    // blocked h [2][4][32][64][8] bf16
    ushort* pre,                     // bf16 [128][4096][64]
    float* __restrict__ out,
    int* flags) {                    // [256] h-flags (4B) | pre_ready @ +1024 ints
  __shared__ char smem[32768];
  const int bid = blockIdx.x;
  const int tid = threadIdx.x;
  int* pre_ready = flags + 1024;

  if (bid >= 256) {
    // ========================= GEMM role =========================
    ushort* At = (ushort*)smem;            // [128][64] swizzled
    ushort* Bt = (ushort*)(smem + 16384);
    const int gb = bid - 256;
    const int m0 = (gb & 31) * 128;
    const int ntile = gb >> 5;             // ascending with dispatch order
    const int n0 = ntile * 128;
    const int wave = tid >> 6, lane = tid & 63;
    const int wm = wave >> 1, wn = wave & 1;
    const int q = lane >> 4, lc = lane & 15;

    f32x4 acc[4][4];
    #pragma unroll
    for (int mt = 0; mt < 4; ++mt)
      #pragma unroll
      for (int nt = 0; nt < 4; ++nt)
        acc[mt][nt] = (f32x4){0.f, 0.f, 0.f, 0.f};

    for (int k0 = 0; k0 < 512; k0 += 64) {
      __syncthreads();
      for (int idx = tid; idx < 1024; idx += 256) {
        int r = idx >> 3, ch = idx & 7;
        const float* ap = Wih + (size_t)(m0 + r) * 1024 + 512 + k0 + ch * 8;
        float4 ax = *(const float4*)ap; float4 ay = *(const float4*)(ap + 4);
        uint4 av; av.x = pack2(ax.x, ax.y); av.y = pack2(ax.z, ax.w);
        av.z = pack2(ay.x, ay.y); av.w = pack2(ay.z, ay.w);
        *reinterpret_cast<uint4*>(&At[r * 64 + (ch ^ (r & 7)) * 8]) = av;
        const float* bp = acts + (size_t)(n0 + r) * 512 + k0 + ch * 8;
        float4 bx = *(const float4*)bp; float4 by = *(const float4*)(bp + 4);
        uint4 bv; bv.x = pack2(bx.x, bx.y); bv.y = pack2(bx.z, bx.w);
        bv.z = pack2(by.x, by.y); bv.w = pack2(by.z, by.w);
        *reinterpret_cast<uint4*>(&Bt[r * 64 + (ch ^ (r & 7)) * 8]) = bv;
      }
      __syncthreads();
      #pragma unroll
      for (int kk = 0; kk < 2; ++kk) {
        bf16x8 af[4], bfr[4];
        #pragma unroll
        for (int mt = 0; mt < 4; ++mt) {
          int r = wm * 64 + mt * 16 + lc;
          af[mt] = *reinterpret_cast<const bf16x8*>(&At[r * 64 + ((kk * 4 + q) ^ (r & 7)) * 8]);
        }
        #pragma unroll
        for (int nt = 0; nt < 4; ++nt) {
          int r = wn * 64 + nt * 16 + lc;
          bfr[nt] = *reinterpret_cast<const bf16x8*>(&Bt[r * 64 + ((kk * 4 + q) ^ (r & 7)) * 8]);
        }
        #pragma unroll
        for (int mt = 0; mt < 4; ++mt)
          #pragma unroll
          for (int nt = 0; nt < 4; ++nt)
            acc[mt][nt] = __builtin_amdgcn_mfma_f32_16x16x32_bf16(af[mt], bfr[nt], acc[mt][nt], 0, 0, 0);
      }
    }
    // epilogue: add base, write pre[l][g][b] via sc0sc1 (MALL write-through)
    #pragma unroll
    for (int mt = 0; mt < 4; ++mt) {
      #pragma unroll
      for (int nt = 0; nt < 4; ++nt) {
        int g = m0 + wm * 64 + mt * 16 + q * 4;
        int lb = n0 + wn * 64 + nt * 16 + lc;
        unsigned l = (unsigned)(lb >> 6), b = (unsigned)(lb & 63);
        #pragma unroll
        for (int i = 0; i < 4; ++i) {
          float v = acc[mt][nt][i] + baseT[(size_t)(g + i) * 64 + b];
          unsigned data = f2bf(v);
          unsigned voff = (l * 262144u + (unsigned)(g + i) * 64u + b) * 2u;
          asm volatile("global_store_short %0, %1, %2 sc0 sc1"
                       :: "v"(voff), "v"(data), "s"(pre) : "memory");
        }
      }
    }
    asm volatile("s_waitcnt vmcnt(0)" ::: "memory");
    __syncthreads();  // all waves drained
    if (tid == 0)
      __hip_atomic_fetch_add(&pre_ready[ntile], 1, __ATOMIC_RELAXED,
                             __HIP_MEMORY_SCOPE_AGENT);
    return;
  }

  // ========================= LSTM role =========================
  const int bq = bid & 3;            // batch-quarter plane
  const int ug = bid >> 2;           // unit group (0..63)
  const int w = tid >> 6;
  const int lane = tid & 63;
  const int q = lane >> 4;
  const int lc = lane & 15;
  const int ul = w * 4 + (lc & 3);
  const int u = ug * 16 + ul;
  const int gr = u + ((lc >> 2) << 10);        // gate row (gate = lc>>2)
  const int bbase = bq * 16 + q * 4;
  const bool cellLane = ((lc & 12) == 0);

  int* cnt = (int*)smem;
  if (tid == 0) { cnt[0] = 0; cnt[1] = 0; }

  // W_hh fragments in registers (f32 -> bf16 with identical rounding)
  bf16x8 wfr[32];
  {
    const float* wr = Whh + (size_t)gr * 1024 + q * 8;
    #pragma unroll
    for (int kk = 0; kk < 32; ++kk) {
      float4 x = *(const float4*)(wr + kk * 32);
      float4 y = *(const float4*)(wr + kk * 32 + 4);
      uint4 p; p.x = pack2(x.x, x.y); p.y = pack2(x.z, x.w);
      p.z = pack2(y.x, y.y); p.w = pack2(y.z, y.w);
      wfr[kk] = *reinterpret_cast<bf16x8*>(&p);
    }
  }
  float cst[4];
  #pragma unroll
  for (int i = 0; i < 4; ++i)
    cst[i] = cellLane ? c0[(size_t)(bbase + i) * 1024 + u] : 0.f;

  __syncthreads();  // cnt init visible

  const unsigned hld = ((unsigned)bq << 15) | ((unsigned)lane << 4);
  const unsigned hst = ((unsigned)((bq * 32 + (u >> 5)) * 512 +
                                   ((u >> 3) & 3) * 128 + (q * 4) * 8 + (u & 7))) * 2u;
  const unsigned pre_base = ((unsigned)(gr * 64 + bbase)) * 2u;
  const int* fp = flags + bq * 64 + lane;   // this lane's producer flag
  const int myflag = bq * 64 + ug;

  // initial gate on pre tile 0, then load pre slice for t=0
  for (;;) {
    int r = __hip_atomic_load(&pre_ready[0], __ATOMIC_RELAXED, __HIP_MEMORY_SCOPE_AGENT);
    if (__all(r >= 32)) break;
    __builtin_amdgcn_s_sleep(2);
  }
  ushort4 pa = *reinterpret_cast<const ushort4*>(pre + (size_t)gr * 64 + bbase);

  for (int t = 0; t < 128; ++t) {
    const int tn = (t < 127) ? t + 1 : t;
    const int tile = tn >> 1;
    // gate: h(t) published by all 64 producers of this plane AND pre tile ready
    for (;;) {
      int f = (t > 0) ? __hip_atomic_load(fp, __ATOMIC_RELAXED, __HIP_MEMORY_SCOPE_AGENT)
                      : 0x7fffffff;
      int r = __hip_atomic_load(&pre_ready[tile], __ATOMIC_RELAXED, __HIP_MEMORY_SCOPE_AGENT);
      if (__all((f >= t) && (r >= 32))) break;
      __builtin_amdgcn_s_sleep(2);
    }

    // issue pre prefetch (t+1) + phased h loads (sc0sc1, bypass to MALL)
    ushort4 npa;
    asm volatile("global_load_dwordx2 %0, %1, %2 sc0 sc1"
                 : "=v"(npa) : "v"(pre_base + (unsigned)tn * 524288u), "s"(pre));
    const unsigned hob = hld | ((unsigned)(t & 1) << 17);
    bf16x8 hA[8], hB[8];
    #pragma unroll
    for (int k = 0; k < 8; ++k)
      asm volatile("global_load_dwordx4 %0, %1, %2 sc0 sc1"
                   : "=v"(hA[k]) : "v"(hob + ((unsigned)k << 10)), "s"(hbuf));
    #pragma unroll
    for (int k = 0; k < 8; ++k)
      asm volatile("global_load_dwordx4 %0, %1, %2 sc0 sc1"
                   : "=v"(hB[k]) : "v"(hob + ((unsigned)(k + 8) << 10)), "s"(hbuf));

    f32x4 acc_a, acc_b;
    acc_a[0] = bf2f(pa.x); acc_a[1] = bf2f(pa.y);
    acc_a[2] = bf2f(pa.z); acc_a[3] = bf2f(pa.w);
    acc_b = (f32x4){0.f, 0.f, 0.f, 0.f};

    WAITG(8)  // pre + hA landed (trailing 8 = hB)
    #pragma unroll
    for (int j = 0; j < 8; ++j)
      acc_a = __builtin_amdgcn_mfma_f32_16x16x32_bf16(hA[j], wfr[j], acc_a, 0, 0, 0);
    __builtin_amdgcn_sched_barrier(0);
    #pragma unroll
    for (int k = 0; k < 8; ++k)  // chunk group C reuses hA regs
      asm volatile("global_load_dwordx4 %0, %1, %2 sc0 sc1"
                   : "=v"(hA[k]) : "v"(hob + ((unsigned)(k + 16) << 10)), "s"(hbuf));
    WAITG(8)  // hB landed (trailing 8 = C)
    #pragma unroll
    for (int j = 0; j < 8; ++j)
      acc_b = __builtin_amdgcn_mfma_f32_16x16x32_bf16(hB[j], wfr[8 + j], acc_b, 0, 0, 0);
    __builtin_amdgcn_sched_barrier(0);
    #pragma unroll
    for (int k = 0; k < 8; ++k)  // chunk group D reuses hB regs
      asm volatile("global_load_dwordx4 %0, %1, %2 sc0 sc1"
                   : "=v"(hB[k]) : "v"(hob + ((unsigned)(k + 24) << 10)), "s"(hbuf));
    WAITG(8)  // C landed (trailing 8 = D)
    #pragma unroll
    for (int j = 0; j < 8; ++j)
      acc_a = __builtin_amdgcn_mfma_f32_16x16x32_bf16(hA[j], wfr[16 + j], acc_a, 0, 0, 0);
    WAITG(0)  // D landed
    #pragma unroll
    for (int j = 0; j < 8; ++j)
      acc_b = __builtin_amdgcn_mfma_f32_16x16x32_bf16(hB[j], wfr[24 + j], acc_b, 0, 0, 0);

    f32x4 acc;
    #pragma unroll
    for (int i = 0; i < 4; ++i) acc[i] = acc_a[i] + acc_b[i];

    // join i/f/g/o across lanes (lc, lc^4, lc^8, lc^12)
    float fv[4], gv[4], ov[4];
    #pragma unroll
    for (int i = 0; i < 4; ++i) {
      fv[i] = __shfl_xor(acc[i], 4, 64);
      gv[i] = __shfl_xor(acc[i], 8, 64);
      ov[i] = __shfl_xor(acc[i], 12, 64);
    }
    float hv[4];
    if (cellLane) {
      #pragma unroll
      for (int i = 0; i < 4; ++i) {
        float ig = 1.f / (1.f + __expf(-acc[i]));
        float fg = 1.f / (1.f + __expf(-fv[i]));
        float gg = tanhf(gv[i]);
        float og = 1.f / (1.f + __expf(-ov[i]));
        float cn = fg * cst[i] + ig * gg;
        hv[i] = og * tanhf(cn);
        cst[i] = cn;
      }
    }

    if (t == 127) {
      if (cellLane) {
        #pragma unroll
        for (int i = 0; i < 4; ++i) {
          int b = bbase + i;
          out[((size_t)t * 64 + b) * 1024 + u] = hv[i];
          out[HN_OFF + (size_t)b * 1024 + u] = hv[i];
          out[CN_OFF + (size_t)b * 1024 + u] = cst[i];
        }
      }
      break;
    }

    // export h(t+1): cellLanes store 4x 2B direct to MALL
    if (cellLane) {
      #pragma unroll
      for (int i = 0; i < 4; ++i) {
        unsigned dv = f2bf(hv[i]);
        unsigned voff = hst + (unsigned)(i * 16) + ((unsigned)((t + 1) & 1) << 17);
        asm volatile("global_store_short %0, %1, %2 sc0 sc1"
                     :: "v"(voff), "v"(dv), "s"(hbuf) : "memory");
      }
    }
    WAITG(0)  // drain this wave's exports (parallel across waves)
    if (lane == 0) {
      int old = atomicAdd(&cnt[t & 1], 1);
      if (old == 3) {  // last wave of this block for step t
        cnt[t & 1] = 0;
        __hip_atomic_store(&flags[myflag], t + 1, __ATOMIC_RELAXED,
                           __HIP_MEMORY_SCOPE_AGENT);
      }
    }
    // hs out-writes overlap other blocks' consumption
    if (cellLane) {
      #pragma unroll
      for (int i = 0; i < 4; ++i)
        out[((size_t)t * 64 + bbase + i) * 1024 + u] = hv[i];
    }
    pa = npa;
  }
}

extern "C" void kernel_launch(void* const* d_in, const int* in_sizes, int n_in,
                              void* d_out, int out_size, void* d_ws, size_t ws_size,
                              hipStream_t stream) {
  const float* input = (const float*)d_in[0];  // (64,512)
  const float* acts  = (const float*)d_in[1];  // (128,64,512)
  const float* h0    = (const float*)d_in[2];  // (64,1024)
  const float* c0    = (const float*)d_in[3];  // (64,1024)
  const float* Wih   = (const float*)d_in[4];  // (4096,1024)
  const float* Whh   = (const float*)d_in[5];  // (4096,1024)
  const float* bih   = (const float*)d_in[6];  // (4096)
  const float* bhh   = (const float*)d_in[7];  // (4096)
  float* out = (float*)d_out;

  char* ws = (char*)d_ws;
  ushort* pre   = (ushort*)(ws);                 // 67,108,864 B  [l][g][b] bf16
  ushort* hbuf  = (ushort*)(ws + 67108864);      //    262,144 B
  int*    flags = (int*)   (ws + 67371008);      //      8,192 B (flags + pre_ready)
  float*  baseT = (float*) (ws + 67379200);      //  1,048,576 B

  hipMemsetAsync(flags, 0, 8192, stream);
  conv_h0<<<32, 256, 0, stream>>>(h0, hbuf);
  base_kernel<<<1024, 256, 0, stream>>>(input, Wih, bih, bhh, baseT);
  mega_kernel<<<2304, 256, 0, stream>>>(Whh, Wih, acts, c0, baseT, hbuf, pre, out, flags);
}

// Round 11
// 789.354 us; speedup vs baseline: 1.6893x; 1.6893x over previous
//
#include <hip/hip_runtime.h>
#include <hip/hip_bf16.h>

typedef __bf16 bf16x8 __attribute__((ext_vector_type(8)));
typedef float f32x4 __attribute__((ext_vector_type(4)));
typedef unsigned long long ull;

// d_out layout (f32): hs[128][64][1024] | h_n[64][1024] | c_n[64][1024]
#define HN_OFF 8388608u
#define CN_OFF 8454144u

__device__ __forceinline__ float bf2f(ushort u) {
  union { unsigned int i; float f; } x; x.i = ((unsigned int)u) << 16; return x.f;
}
__device__ __forceinline__ ushort f2bf(float f) {
  union { float f; unsigned int i; } x; x.f = f;
  unsigned int r = x.i + 0x7FFFu + ((x.i >> 16) & 1u);
  return (ushort)(r >> 16);
}
__device__ __forceinline__ unsigned pack2(float a, float b) {
  return (unsigned)f2bf(a) | ((unsigned)f2bf(b) << 16);
}

// h0 (64x1024 f32) -> blocked bf16 layout [bq(4)][kk(32)][lane(64)][8]
__global__ __launch_bounds__(256) void conv_h0(const float* __restrict__ h0,
                                               ushort* __restrict__ hb) {
  int t = blockIdx.x * 256 + threadIdx.x;
  int b = t >> 7, c = t & 127;  // j = c*8
  float4 v0 = *reinterpret_cast<const float4*>(h0 + (size_t)b * 1024 + c * 8);
  float4 v1 = *reinterpret_cast<const float4*>(h0 + (size_t)b * 1024 + c * 8 + 4);
  size_t de = ((size_t)(b >> 4) * 32 + (c >> 2)) * 512 + (size_t)(c & 3) * 128 + (b & 15) * 8;
  ushort* d = hb + de;
  d[0] = f2bf(v0.x); d[1] = f2bf(v0.y); d[2] = f2bf(v0.z); d[3] = f2bf(v0.w);
  d[4] = f2bf(v1.x); d[5] = f2bf(v1.y); d[6] = f2bf(v1.z); d[7] = f2bf(v1.w);
}

// ---------------- base[g][b] = input[b]·W_x[g] + b_ih[g] + b_hh[g] ----------------
__global__ __launch_bounds__(256) void base_kernel(const float* __restrict__ x,
    const float* __restrict__ Wih, const float* __restrict__ bih,
    const float* __restrict__ bhh, float* __restrict__ baseT) {
  int t = blockIdx.x * 256 + threadIdx.x;
  int g = t >> 6, b = t & 63;
  const float4* xv = reinterpret_cast<const float4*>(x + (size_t)b * 512);
  const float4* wv = reinterpret_cast<const float4*>(Wih + (size_t)g * 1024);
  float s = 0.f;
  #pragma unroll 4
  for (int a = 0; a < 128; ++a) {
    float4 xa = xv[a], wa = wv[a];
    s += xa.x * wa.x + xa.y * wa.y + xa.z * wa.z + xa.w * wa.w;
  }
  baseT[t] = s + bih[g] + bhh[g];
}

// -------- pre[g][lb] = sum_a Wa[g][a]*acts[lb][a] + base[g][lb%64] (f32 in) --------
__global__ __launch_bounds__(256, 1) void gemm_pre(
    const float* __restrict__ Wih,   // f32 [4096][1024], cols 512.. = W_a
    const float* __restrict__ acts,  // f32 [8192][512]
    const float* __restrict__ baseT, // f32 [4096][64]
    ushort* __restrict__ C) {        // bf16 [4096][8192]
  __shared__ ushort At[128 * 64];
  __shared__ ushort Bt[128 * 64];
  const int tid = threadIdx.x;
  const int m0 = blockIdx.x * 128;
  const int n0 = blockIdx.y * 128;
  const int wave = tid >> 6, lane = tid & 63;
  const int wm = wave >> 1, wn = wave & 1;
  const int q = lane >> 4, lc = lane & 15;

  f32x4 acc[4][4];
  #pragma unroll
  for (int mt = 0; mt < 4; ++mt)
    #pragma unroll
    for (int nt = 0; nt < 4; ++nt)
      acc[mt][nt] = (f32x4){0.f, 0.f, 0.f, 0.f};

  for (int k0 = 0; k0 < 512; k0 += 64) {
    __syncthreads();
    for (int idx = tid; idx < 1024; idx += 256) {
      int r = idx >> 3, ch = idx & 7;
      const float* ap = Wih + (size_t)(m0 + r) * 1024 + 512 + k0 + ch * 8;
      float4 ax = *(const float4*)ap; float4 ay = *(const float4*)(ap + 4);
      uint4 av; av.x = pack2(ax.x, ax.y); av.y = pack2(ax.z, ax.w);
      av.z = pack2(ay.x, ay.y); av.w = pack2(ay.z, ay.w);
      *reinterpret_cast<uint4*>(&At[r * 64 + (ch ^ (r & 7)) * 8]) = av;
      const float* bp = acts + (size_t)(n0 + r) * 512 + k0 + ch * 8;
      float4 bx = *(const float4*)bp; float4 by = *(const float4*)(bp + 4);
      uint4 bv; bv.x = pack2(bx.x, bx.y); bv.y = pack2(bx.z, bx.w);
      bv.z = pack2(by.x, by.y); bv.w = pack2(by.z, by.w);
      *reinterpret_cast<uint4*>(&Bt[r * 64 + (ch ^ (r & 7)) * 8]) = bv;
    }
    __syncthreads();
    #pragma unroll
    for (int kk = 0; kk < 2; ++kk) {
      bf16x8 af[4], bfr[4];
      #pragma unroll
      for (int mt = 0; mt < 4; ++mt) {
        int r = wm * 64 + mt * 16 + lc;
        af[mt] = *reinterpret_cast<const bf16x8*>(&At[r * 64 + ((kk * 4 + q) ^ (r & 7)) * 8]);
      }
      #pragma unroll
      for (int nt = 0; nt < 4; ++nt) {
        int r = wn * 64 + nt * 16 + lc;
        bfr[nt] = *reinterpret_cast<const bf16x8*>(&Bt[r * 64 + ((kk * 4 + q) ^ (r & 7)) * 8]);
      }
      #pragma unroll
      for (int mt = 0; mt < 4; ++mt)
        #pragma unroll
        for (int nt = 0; nt < 4; ++nt)
          acc[mt][nt] = __builtin_amdgcn_mfma_f32_16x16x32_bf16(af[mt], bfr[nt], acc[mt][nt], 0, 0, 0);
    }
  }
  #pragma unroll
  for (int mt = 0; mt < 4; ++mt) {
    #pragma unroll
    for (int nt = 0; nt < 4; ++nt) {
      int g = m0 + wm * 64 + mt * 16 + q * 4;
      int lb = n0 + wn * 64 + nt * 16 + lc;
      int b = lb & 63;
      #pragma unroll
      for (int i = 0; i < 4; ++i) {
        float v = acc[mt][nt][i] + baseT[(size_t)(g + i) * 64 + b];
        C[(size_t)(g + i) * 8192 + lb] = f2bf(v);
      }
    }
  }
}

// ---------------- persistent LSTM recurrence: W in regs, K-split waves ------
// 256 blocks x 256 threads. Block (ug = bid>>2, bq = bid&3). Wave w loads ONLY
// h chunks w*8..w*8+7 (8 KB; 8 MB/step MALL, was 32) and computes partials for
// ALL 4 gate-row tiles (wfr[4][8] = 128 VGPR, loaded once from f32). Partials
// exchanged via 16 KB LDS; wave w reduces tile w -> identical cell/export path
// to R6 (proven). Counted-vmcnt ladder keeps load->MFMA overlap.
#define WAITG(n) asm volatile("s_waitcnt vmcnt(" #n ")" ::: "memory"); \
                 __builtin_amdgcn_sched_barrier(0);

__global__ __launch_bounds__(256, 1) void lstm_rec(
    const float* __restrict__ Whh,   // f32 [4096][1024]
    const ushort* __restrict__ pre,  // bf16 [4096][8192]
    const float* __restrict__ c0,    // f32 [64][1024]
    const ushort* __restrict__ hbuf, // blocked bf16 [2][4][32][64][8] (read)
    ushort* __restrict__ hbw,        // same buffer, write alias
    float* __restrict__ out,
    int* __restrict__ flags) {       // [4 planes][64] ints at 16B stride
  __shared__ f32x4 part[4][4][64];   // [producer wave][tile][lane] : 16 KB
  __shared__ ushort hstage[16 * 16];
  const int tid = threadIdx.x;
  const int bid = blockIdx.x;
  const int bq = bid & 3;
  const int ug = bid >> 2;
  const int w = tid >> 6;
  const int lane = tid & 63;
  const int q = lane >> 4;
  const int lc = lane & 15;
  const int ul = w * 4 + (lc & 3);             // unit-local for CELL phase
  const int u = ug * 16 + ul;
  const int gr = u + ((lc >> 2) << 10);        // gate row for cell tile (= tile w)
  const int bbase = bq * 16 + q * 4;
  const bool cellLane = ((lc & 12) == 0);

  // W fragments: tile T (T=0..3) rows, this wave's K chunks w*8..w*8+7
  bf16x8 wfr[4][8];
  #pragma unroll
  for (int T = 0; T < 4; ++T) {
    const int grT = ug * 16 + T * 4 + (lc & 3) + ((lc >> 2) << 10);
    #pragma unroll
    for (int k = 0; k < 8; ++k) {
      const float* wp = Whh + (size_t)grT * 1024 + (w * 8 + k) * 32 + q * 8;
      float4 x = *(const float4*)wp;
      float4 y = *(const float4*)(wp + 4);
      uint4 p; p.x = pack2(x.x, x.y); p.y = pack2(x.z, x.w);
      p.z = pack2(y.x, y.y); p.w = pack2(y.z, y.w);
      wfr[T][k] = *reinterpret_cast<bf16x8*>(&p);
    }
  }

  float cst[4];
  #pragma unroll
  for (int i = 0; i < 4; ++i)
    cst[i] = cellLane ? c0[(size_t)(bbase + i) * 1024 + u] : 0.f;

  const unsigned va_base = ((unsigned)gr * 8192u + (unsigned)bbase) * 2u;
  const unsigned hob0 = ((unsigned)bq << 15) | ((unsigned)lane << 4);
  const int* fp = flags + (bq * 64 + lane) * 4;  // per-lane flag to poll
  const int myflag = (bq * 64 + ug) * 4;

  // pre slice for t=0
  ushort4 pa = *reinterpret_cast<const ushort4*>(pre + (size_t)gr * 8192 + bbase);

  for (int t = 0; t < 128; ++t) {
    // gate: every wave spins on all 64 producer flags of its plane
    if (t > 0) {
      for (;;) {
        int f = __hip_atomic_load(fp, __ATOMIC_RELAXED, __HIP_MEMORY_SCOPE_AGENT);
        if (__all(f >= t)) break;
      }
    }

    // issue pre prefetch (t+1, cached) + this wave's 8 h-chunk loads (sc0sc1)
    const int tn = (t < 127) ? t + 1 : t;
    ushort4 npa;
    asm volatile("global_load_dwordx2 %0, %1, %2"
                 : "=v"(npa) : "v"(va_base + (unsigned)tn * 128u), "s"(pre));
    const unsigned hob = hob0 | ((unsigned)(t & 1) << 17);
    bf16x8 haf[8];
    #pragma unroll
    for (int k = 0; k < 8; ++k)
      asm volatile("global_load_dwordx4 %0, %1, %2 sc0 sc1"
                   : "=v"(haf[k]) : "v"(hob + ((unsigned)(w * 8 + k) << 10)), "s"(hbuf));

    // partials for all 4 tiles over this wave's 8 chunks (counted-vmcnt ladder)
    f32x4 p0 = (f32x4){0.f,0.f,0.f,0.f}, p1 = p0, p2 = p0, p3 = p0;
    WAITG(4)  // oldest done: [4 out-stores] + pre + h0..h3
    #pragma unroll
    for (int k = 0; k < 4; ++k) {
      p0 = __builtin_amdgcn_mfma_f32_16x16x32_bf16(haf[k], wfr[0][k], p0, 0, 0, 0);
      p1 = __builtin_amdgcn_mfma_f32_16x16x32_bf16(haf[k], wfr[1][k], p1, 0, 0, 0);
      p2 = __builtin_amdgcn_mfma_f32_16x16x32_bf16(haf[k], wfr[2][k], p2, 0, 0, 0);
      p3 = __builtin_amdgcn_mfma_f32_16x16x32_bf16(haf[k], wfr[3][k], p3, 0, 0, 0);
    }
    WAITG(0)
    #pragma unroll
    for (int k = 4; k < 8; ++k) {
      p0 = __builtin_amdgcn_mfma_f32_16x16x32_bf16(haf[k], wfr[0][k], p0, 0, 0, 0);
      p1 = __builtin_amdgcn_mfma_f32_16x16x32_bf16(haf[k], wfr[1][k], p1, 0, 0, 0);
      p2 = __builtin_amdgcn_mfma_f32_16x16x32_bf16(haf[k], wfr[2][k], p2, 0, 0, 0);
      p3 = __builtin_amdgcn_mfma_f32_16x16x32_bf16(haf[k], wfr[3][k], p3, 0, 0, 0);
    }
    part[w][0][lane] = p0; part[w][1][lane] = p1;
    part[w][2][lane] = p2; part[w][3][lane] = p3;
    __syncthreads();  // sync A: partials visible

    // reduce tile w: acc = pre + sum over producer waves
    f32x4 acc;
    acc[0] = bf2f(pa.x); acc[1] = bf2f(pa.y); acc[2] = bf2f(pa.z); acc[3] = bf2f(pa.w);
    #pragma unroll
    for (int wp = 0; wp < 4; ++wp) {
      f32x4 pr = part[wp][w][lane];
      #pragma unroll
      for (int i = 0; i < 4; ++i) acc[i] += pr[i];
    }

    // join i/f/g/o across lanes (lc, lc^4, lc^8, lc^12), then LSTM cell
    float fv[4], gv[4], ov[4];
    #pragma unroll
    for (int i = 0; i < 4; ++i) {
      fv[i] = __shfl_xor(acc[i], 4, 64);
      gv[i] = __shfl_xor(acc[i], 8, 64);
      ov[i] = __shfl_xor(acc[i], 12, 64);
    }
    float hv[4];
    if (cellLane) {
      #pragma unroll
      for (int i = 0; i < 4; ++i) {
        float ig = 1.f / (1.f + __expf(-acc[i]));
        float fg = 1.f / (1.f + __expf(-fv[i]));
        float gg = tanhf(gv[i]);
        float og = 1.f / (1.f + __expf(-ov[i]));
        float cn = fg * cst[i] + ig * gg;
        hv[i] = og * tanhf(cn);
        cst[i] = cn;
        hstage[(q * 4 + i) * 16 + ul] = f2bf(hv[i]);
      }
    }

    if (t == 127) {
      if (cellLane) {
        #pragma unroll
        for (int i = 0; i < 4; ++i) {
          int b = bbase + i;
          out[((size_t)t * 64 + b) * 1024 + u] = hv[i];
          out[HN_OFF + (size_t)b * 1024 + u] = hv[i];
          out[CN_OFF + (size_t)b * 1024 + u] = cst[i];
        }
      }
      break;
    }

    __syncthreads();  // sync B: hstage ready (also protects part reuse)

    // export h(t+1): wave 0 only (32 threads x 16B), drain, publish (R6-proven)
    if (tid < 32) {
      int bl = tid >> 1, ci = tid & 1;
      const ull* src = reinterpret_cast<const ull*>(&hstage[bl * 16 + ci * 8]);
      size_t de = ((size_t)((t + 1) & 1) << 16) + ((size_t)bq << 14) +
                  ((size_t)(ug >> 1) << 9) +
                  (size_t)(((ug * 2 + ci) & 3) * 16 + bl) * 8;
      ull* dst = reinterpret_cast<ull*>(hbw + de);
      __hip_atomic_store(dst, src[0], __ATOMIC_RELAXED, __HIP_MEMORY_SCOPE_AGENT);
      __hip_atomic_store(dst + 1, src[1], __ATOMIC_RELAXED, __HIP_MEMORY_SCOPE_AGENT);
    }
    if (w == 0) {
      asm volatile("s_waitcnt vmcnt(0)" ::: "memory");
      if (tid == 0)
        __hip_atomic_store(&flags[myflag], t + 1, __ATOMIC_RELAXED,
                           __HIP_MEMORY_SCOPE_AGENT);
    }

    // hs out-writes overlap other blocks' consumption (4 stores, counted in ladder)
    if (cellLane) {
      #pragma unroll
      for (int i = 0; i < 4; ++i)
        out[((size_t)t * 64 + bbase + i) * 1024 + u] = hv[i];
    }

    pa = npa;
  }
}

extern "C" void kernel_launch(void* const* d_in, const int* in_sizes, int n_in,
                              void* d_out, int out_size, void* d_ws, size_t ws_size,
                              hipStream_t stream) {
  const float* input = (const float*)d_in[0];  // (64,512)
  const float* acts  = (const float*)d_in[1];  // (128,64,512)
  const float* h0    = (const float*)d_in[2];  // (64,1024)
  const float* c0    = (const float*)d_in[3];  // (64,1024)
  const float* Wih   = (const float*)d_in[4];  // (4096,1024)
  const float* Whh   = (const float*)d_in[5];  // (4096,1024)
  const float* bih   = (const float*)d_in[6];  // (4096)
  const float* bhh   = (const float*)d_in[7];  // (4096)
  float* out = (float*)d_out;

  char* ws = (char*)d_ws;
  ushort* pre   = (ushort*)(ws);                 // 67,108,864 B  [g][lb] bf16
  ushort* hbuf  = (ushort*)(ws + 67108864);      //    262,144 B
  int*    flags = (int*)   (ws + 67371008);      //      8,192 B
  float*  baseT = (float*) (ws + 67379200);      //  1,048,576 B

  hipMemsetAsync(flags, 0, 8192, stream);
  conv_h0<<<32, 256, 0, stream>>>(h0, hbuf);
  base_kernel<<<1024, 256, 0, stream>>>(input, Wih, bih, bhh, baseT);
  gemm_pre<<<dim3(32, 64), 256, 0, stream>>>(Wih, acts, baseT, pre);
  lstm_rec<<<256, 256, 0, stream>>>(Whh, pre, c0, hbuf, hbuf, out, flags);
}